// Round 2
// baseline (234.660 us; speedup 1.0000x reference)
//
#include <hip/hip_runtime.h>
#include <hip/hip_bf16.h>
#include <math.h>

// MHA B=8,S=2048,D=512,H=8,LAT=64,OUT=64. fp32 in/out.
// R15: qkv_mfma rebuilt — block per (s-tile,b), h-loop inside:
//  - x tile (64x512) converted+staged ONCE (was 8x, once per head): x HBM /8,
//    pack VALU /8, LDS staging /8
//  - W slice (192x64) double-buffered via global_load_lds, pre-swizzled source,
//    ONE barrier per K-step (flash R14 recipe)
//  - 8 waves, 2x4 (s x n) wave split; per-head epilogue via reused LDS stage
// flash_mfma/out_mfma/wprep unchanged from R14 (flash verified at 102us).
static constexpr int Bn = 8, Sn = 2048, Dn = 512, Hn = 8, LATn = 64, OUTn = 64;

typedef short  bf16x8 __attribute__((ext_vector_type(8)));
typedef float  f32x4  __attribute__((ext_vector_type(4)));

__device__ __forceinline__ unsigned short f2bf(float f) {   // RNE (prep kernels)
    union { float f; unsigned int i; } v; v.f = f;
    unsigned int x = v.i;
    return (unsigned short)((x + 0x7FFFu + ((x >> 16) & 1u)) >> 16);
}
// pack two floats -> two bf16 (round-half-up: bias 2^-17 rel, ~RNE quality)
__device__ __forceinline__ unsigned int pack2bf(float a, float b) {
    unsigned int ua = __float_as_uint(a) + 0x8000u;
    unsigned int ub = __float_as_uint(b) + 0x8000u;
    return (ua >> 16) | (ub & 0xFFFF0000u);
}

#if __has_builtin(__builtin_amdgcn_exp2f)
#define EXP2(x) __builtin_amdgcn_exp2f(x)
#else
#define EXP2(x) exp2f(x)
#endif

// async 16B global->LDS; vmcnt-tracked; LDS dest = wave-uniform base + lane*16
__device__ __forceinline__ void gl_lds16(const void* g, void* l) {
    __builtin_amdgcn_global_load_lds(
        (const __attribute__((address_space(1))) unsigned int*)g,
        (__attribute__((address_space(3))) unsigned int*)l, 16, 0, 0);
}

// ---------------- Kernel 0: weight prep -------------------------------------
// WT[h][192][512] bf16 (Q slice scaled by 0.125*log2e), then WOT[64][512].
__global__ __launch_bounds__(256) void wprep(
    const float* __restrict__ WQ, const float* __restrict__ WK,
    const float* __restrict__ WV, const float* __restrict__ WO,
    unsigned short* __restrict__ WT)
{
    __shared__ float tile[64][65];
    const int t  = threadIdx.x;
    const int d0 = blockIdx.x * 64;
    const int yy = blockIdx.y;

    const float* W; float scale = 1.0f; size_t dstbase;
    if (yy < 24) {
        int h = yy / 3, which = yy % 3;
        W = (which == 0) ? WQ : (which == 1) ? WK : WV;
        W += (size_t)h * Dn * 64;
        if (which == 0) scale = 0.125f * 1.44269504088896f;   // fold 1/8 * log2(e)
        dstbase = ((size_t)h * 192 + which * 64) * Dn;
    } else {
        W = WO;                                                // [512][64]
        dstbase = (size_t)8 * 192 * Dn;                        // WOT after QKV
    }

    for (int i = 0; i < 4; ++i) {
        int idx = i * 256 + t;
        int r = idx >> 4, c = (idx & 15) * 4;
        float4 u = *(const float4*)(W + (size_t)(d0 + r) * 64 + c);
        tile[r][c] = u.x; tile[r][c+1] = u.y; tile[r][c+2] = u.z; tile[r][c+3] = u.w;
    }
    __syncthreads();
    const int n = t & 63, dd = t >> 6;
    unsigned short pk[16];
    for (int i = 0; i < 16; ++i) pk[i] = f2bf(tile[dd*16 + i][n] * scale);
    size_t dst = dstbase + (size_t)n * Dn + d0 + dd * 16;
    *(bf16x8*)(WT + dst)     = *(bf16x8*)(pk);
    *(bf16x8*)(WT + dst + 8) = *(bf16x8*)(pk + 8);
}

// ---------------- Kernel 1: MFMA QKV projection (R15 rebuild) ---------------
// Block = (s-tile 64, b). x tile resident in LDS (bf16, XOR-swizzled), h-loop
// with W-slice double-buffer via global_load_lds. Outputs per head via LDS
// stage: Qb/Kb row-major [bh][s][64], VT [bh][o][s].
__global__ __launch_bounds__(512, 2) void qkv_mfma(
    const float* __restrict__ x, const unsigned short* __restrict__ WT,
    unsigned short* __restrict__ Qb, unsigned short* __restrict__ Kb,
    unsigned short* __restrict__ VT)
{
    __shared__ __align__(16) unsigned short Xs[64 * 512];      // 64 KB resident
    __shared__ __align__(16) unsigned short Ws[2][192 * 64];   // 48 KB dbuf
    __shared__ __align__(16) unsigned short Os[64 * 200];      // 25 KB epilogue

    const int t  = threadIdx.x;
    const int w  = t >> 6, ln = t & 63;
    const int nl = ln & 15, g = ln >> 4;
    const int b  = blockIdx.y;
    const int s0 = blockIdx.x * 64;
    const int wm = w >> 2;                         // s-half (0..1)
    const int wn = w & 3;                          // n-quarter (0..3)

    // ---- prologue: x fp32 -> bf16, chunk-swizzled, resident tile ----
    // wave w handles rows r=8i+w (r&7==w); lane ln -> 8 floats at col 8ln,
    // stored at lds chunk (ln ^ w)  =>  lds(r,c) holds global(r, c^(r&7)).
    #pragma unroll
    for (int i = 0; i < 8; ++i) {
        const int r = 8 * i + w;
        const float* src = x + ((size_t)b * Sn + s0 + r) * Dn + 8 * ln;
        float4 u0 = *(const float4*)(src);
        float4 u1 = *(const float4*)(src + 4);
        unsigned int pk[4] = { pack2bf(u0.x, u0.y), pack2bf(u0.z, u0.w),
                               pack2bf(u1.x, u1.y), pack2bf(u1.z, u1.w) };
        *(bf16x8*)(Xs + r * 512 + ((ln ^ w) * 8)) = *(bf16x8*)pk;
    }

    // W slice stage: dest [192][8 chunks] linear; lds(n,c)=global(n,c^(n&7));
    // n&7 == ln>>3 per lane => src chunk col = (ln&7)^(ln>>3).
    const int nbase = w * 8 + (ln >> 3);
    const int csw   = ((ln & 7) ^ (ln >> 3)) * 8;
    auto stageW = [&](int h, int k0, int bufi) {
        #pragma unroll
        for (int i = 0; i < 3; ++i) {
            const int n = i * 64 + nbase;
            gl_lds16(WT + ((size_t)h * 192 + n) * Dn + k0 + csw,
                     Ws[bufi] + (size_t)i * 4096 + w * 512);
        }
    };

    stageW(0, 0, 0);
    __syncthreads();                               // Xs + first W slice ready

    int buf = 0;
    for (int h = 0; h < Hn; ++h) {
        f32x4 acc[2][3];
        #pragma unroll
        for (int m = 0; m < 2; ++m)
            #pragma unroll
            for (int j = 0; j < 3; ++j) acc[m][j] = (f32x4){0.f, 0.f, 0.f, 0.f};

        for (int ks = 0; ks < 8; ++ks) {
            int nh = h, nks = ks + 1;              // prefetch next slice
            if (nks == 8) { nks = 0; ++nh; }
            if (nh < Hn) stageW(nh, nks * 64, buf ^ 1);

            const unsigned short* Wb = Ws[buf];
            const int k0 = ks * 64;
            #pragma unroll
            for (int kc = 0; kc < 2; ++kc) {
                const int sc = ((4 * kc + g) ^ (nl & 7)) * 8;  // swizzled chunk
                bf16x8 a0 = *(const bf16x8*)(Xs + (32*wm      + nl) * 512 + k0 + sc);
                bf16x8 a1 = *(const bf16x8*)(Xs + (32*wm + 16 + nl) * 512 + k0 + sc);
                bf16x8 b0 = *(const bf16x8*)(Wb + (48*wn      + nl) * 64 + sc);
                bf16x8 b1 = *(const bf16x8*)(Wb + (48*wn + 16 + nl) * 64 + sc);
                bf16x8 b2 = *(const bf16x8*)(Wb + (48*wn + 32 + nl) * 64 + sc);
                acc[0][0] = __builtin_amdgcn_mfma_f32_16x16x32_bf16(a0, b0, acc[0][0], 0, 0, 0);
                acc[0][1] = __builtin_amdgcn_mfma_f32_16x16x32_bf16(a0, b1, acc[0][1], 0, 0, 0);
                acc[0][2] = __builtin_amdgcn_mfma_f32_16x16x32_bf16(a0, b2, acc[0][2], 0, 0, 0);
                acc[1][0] = __builtin_amdgcn_mfma_f32_16x16x32_bf16(a1, b0, acc[1][0], 0, 0, 0);
                acc[1][1] = __builtin_amdgcn_mfma_f32_16x16x32_bf16(a1, b1, acc[1][1], 0, 0, 0);
                acc[1][2] = __builtin_amdgcn_mfma_f32_16x16x32_bf16(a1, b2, acc[1][2], 0, 0, 0);
            }
            __syncthreads();                       // drains prefetch + buf reads
            buf ^= 1;
        }

        // ---- epilogue head h: acc -> Os -> Qb/Kb/VT ----
        const int bh = b * 8 + h;
        #pragma unroll
        for (int m = 0; m < 2; ++m)                // C: col=lane&15, row=4g+reg
            #pragma unroll
            for (int j = 0; j < 3; ++j) {
                const int n = 48 * wn + 16 * j + nl;
                #pragma unroll
                for (int r = 0; r < 4; ++r)
                    Os[(32*wm + 16*m + 4*g + r) * 200 + n] = f2bf(acc[m][j][r]);
            }
        __syncthreads();
        for (int i = 0; i < 2; ++i) {              // Qb/Kb row-major
            int idx = i * 512 + t;
            int r = idx >> 4, c = (idx & 15) * 8;
            bf16x8 v = *(const bf16x8*)(Os + r * 200 + c);
            size_t o = ((size_t)bh * Sn + s0 + r) * 64;
            if (c < 64) *(bf16x8*)(Qb + o + c)      = v;
            else        *(bf16x8*)(Kb + o + c - 64) = v;
        }
        {                                          // VT[bh][o][s]
            int o = t & 63, cc = t >> 6;
            unsigned short pk[8];
            #pragma unroll
            for (int i = 0; i < 8; ++i) pk[i] = Os[(8*cc + i) * 200 + 128 + o];
            *(bf16x8*)(VT + ((size_t)bh * 64 + o) * Sn + s0 + 8*cc) = *(bf16x8*)pk;
        }
        __syncthreads();                           // Os reuse by next head
    }
}

// ---------------- Kernel 2: MFMA flash attention (R14, verified) ------------
// 8 waves x 32 q-rows; K/V async-staged (global_load_lds, dbuf, XOR swizzle);
// one barrier per k-tile; P via per-wave swizzled Pt; O stored direct.
__global__ __launch_bounds__(512, 4) void flash_mfma(
    const unsigned short* __restrict__ Qb,
    const unsigned short* __restrict__ Kb,
    const unsigned short* __restrict__ VT,
    unsigned short* __restrict__ Ob)
{
    __shared__ __align__(16) unsigned short KV[2][2][4096];   // 32 KB
    __shared__ __align__(16) unsigned short Pt[8][2048];      // 32 KB, per-wave

    const int t  = threadIdx.x;
    const int w  = t >> 6, ln = t & 63;
    const int qh = ln & 15, g = (ln >> 4) & 3;
    const int bh = blockIdx.y, b = bh >> 3, h = bh & 7;
    const int q0 = blockIdx.x * 256;
    const int qw = q0 + 32 * w;                    // this wave's 32 q rows

    bf16x8 bq[2][2];
    #pragma unroll
    for (int qs = 0; qs < 2; ++qs) {
        const unsigned short* qp =
            Qb + ((size_t)bh * Sn + qw + 16*qs + qh) * 64 + 8*g;
        bq[qs][0] = *(const bf16x8*)(qp);
        bq[qs][1] = *(const bf16x8*)(qp + 32);
    }

    const int r0 = t >> 3;                         // tile row 0..63
    const int cs = (t & 7) ^ (r0 & 7);             // swizzled source chunk col
    const unsigned short* kg = Kb + ((size_t)bh * Sn + r0) * 64 + cs * 8;
    const unsigned short* vg = VT + ((size_t)bh * 64 + r0) * Sn + cs * 8;

    const int swz8  = (qh & 7) * 8;
    const int koff0 = qh*64 + (((g    ) ^ (qh & 7)) * 8);
    const int koff1 = qh*64 + (((4 + g) ^ (qh & 7)) * 8);

    f32x4 o_acc[2][4];
    #pragma unroll
    for (int qs = 0; qs < 2; ++qs)
        #pragma unroll
        for (int f = 0; f < 4; ++f) o_acc[qs][f] = (f32x4){0.f, 0.f, 0.f, 0.f};
    float l_run[2] = {0.f, 0.f};

    gl_lds16(kg, &KV[0][0][w * 512]);
    gl_lds16(vg, &KV[0][1][w * 512]);
    __syncthreads();

    int buf = 0;
    for (int kt = 0; kt < Sn / 64; ++kt) {
        if (kt < Sn / 64 - 1) {                    // prefetch next tile (async)
            kg += 4096; vg += 64;
            gl_lds16(kg, &KV[buf ^ 1][0][w * 512]);
            gl_lds16(vg, &KV[buf ^ 1][1][w * 512]);
        }
        const unsigned short* Kt = KV[buf][0];
        const unsigned short* Vt = KV[buf][1];

        f32x4 st[2][4];
        #pragma unroll
        for (int qs = 0; qs < 2; ++qs)
            #pragma unroll
            for (int f = 0; f < 4; ++f) st[qs][f] = (f32x4){0.f, 0.f, 0.f, 0.f};
        #pragma unroll
        for (int kc = 0; kc < 2; ++kc) {
            const int ko = kc ? koff1 : koff0;
            bf16x8 a0 = *(const bf16x8*)(Kt + ko);
            bf16x8 a1 = *(const bf16x8*)(Kt + ko + 1024);
            bf16x8 a2 = *(const bf16x8*)(Kt + ko + 2048);
            bf16x8 a3 = *(const bf16x8*)(Kt + ko + 3072);
            #pragma unroll
            for (int qs = 0; qs < 2; ++qs) {
                st[qs][0] = __builtin_amdgcn_mfma_f32_16x16x32_bf16(a0, bq[qs][kc], st[qs][0], 0, 0, 0);
                st[qs][1] = __builtin_amdgcn_mfma_f32_16x16x32_bf16(a1, bq[qs][kc], st[qs][1], 0, 0, 0);
                st[qs][2] = __builtin_amdgcn_mfma_f32_16x16x32_bf16(a2, bq[qs][kc], st[qs][2], 0, 0, 0);
                st[qs][3] = __builtin_amdgcn_mfma_f32_16x16x32_bf16(a3, bq[qs][kc], st[qs][3], 0, 0, 0);
            }
        }

        #pragma unroll
        for (int qs = 0; qs < 2; ++qs) {
            float ls = 0.f;
            unsigned short* pw = Pt[w] + qs*1024 + qh*64;
            #pragma unroll
            for (int f = 0; f < 4; ++f) {
                float p0 = EXP2(st[qs][f][0]);
                float p1 = EXP2(st[qs][f][1]);
                float p2 = EXP2(st[qs][f][2]);
                float p3 = EXP2(st[qs][f][3]);
                ls += (p0 + p1) + (p2 + p3);
                *(uint2*)(pw + ((16*f + 4*g) ^ swz8)) =
                    make_uint2(pack2bf(p0, p1), pack2bf(p2, p3));
            }
            ls += __shfl_xor(ls, 16);
            ls += __shfl_xor(ls, 32);
            l_run[qs] += ls;
        }

        #pragma unroll
        for (int kc = 0; kc < 2; ++kc) {
            const int ko = kc ? koff1 : koff0;
            bf16x8 v0 = *(const bf16x8*)(Vt + ko);
            bf16x8 v1 = *(const bf16x8*)(Vt + ko + 1024);
            bf16x8 v2 = *(const bf16x8*)(Vt + ko + 2048);
            bf16x8 v3 = *(const bf16x8*)(Vt + ko + 3072);
            #pragma unroll
            for (int qs = 0; qs < 2; ++qs) {
                bf16x8 bp = *(const bf16x8*)(Pt[w] + qs*1024 + qh*64
                                             + ((32*kc + 8*g) ^ swz8));
                o_acc[qs][0] = __builtin_amdgcn_mfma_f32_16x16x32_bf16(v0, bp, o_acc[qs][0], 0, 0, 0);
                o_acc[qs][1] = __builtin_amdgcn_mfma_f32_16x16x32_bf16(v1, bp, o_acc[qs][1], 0, 0, 0);
                o_acc[qs][2] = __builtin_amdgcn_mfma_f32_16x16x32_bf16(v2, bp, o_acc[qs][2], 0, 0, 0);
                o_acc[qs][3] = __builtin_amdgcn_mfma_f32_16x16x32_bf16(v3, bp, o_acc[qs][3], 0, 0, 0);
            }
        }

        __syncthreads();
        buf ^= 1;
    }

    #pragma unroll
    for (int qs = 0; qs < 2; ++qs) {
        float inv_l = 1.f / l_run[qs];
        unsigned short* op = Ob
            + ((size_t)(b * Sn + q0 + 32*w + 16*qs + qh)) * 512 + h*64 + 4*g;
        #pragma unroll
        for (int f = 0; f < 4; ++f) {
            unsigned int lo = pack2bf(o_acc[qs][f][0] * inv_l, o_acc[qs][f][1] * inv_l);
            unsigned int hi = pack2bf(o_acc[qs][f][2] * inv_l, o_acc[qs][f][3] * inv_l);
            *(uint2*)(op + 16*f) = make_uint2(lo, hi);
        }
    }
}

// ---------------- Kernel 3: MFMA output projection --------------------------
// out[bs][n] = Ob[bs][0:512] @ WOT^T ; A=Ob rows, B=WOT[n][k]. fp32 out.
__global__ __launch_bounds__(256) void out_mfma(
    const unsigned short* __restrict__ Ob, const unsigned short* __restrict__ WOT,
    float* __restrict__ out)
{
    __shared__ __align__(16) unsigned short As[64 * 72];
    __shared__ __align__(16) unsigned short Bs[64 * 72];

    const int t  = threadIdx.x;
    const int w  = t >> 6, ln = t & 63;
    const int qh = ln & 15, g = ln >> 4;
    const int bs0 = blockIdx.x * 64;

    f32x4 acc[4];
    for (int n = 0; n < 4; ++n) acc[n] = (f32x4){0.f, 0.f, 0.f, 0.f};

    for (int k0 = 0; k0 < 512; k0 += 64) {
        __syncthreads();
        for (int i = 0; i < 2; ++i) {
            int idx = i * 256 + t;
            int r = idx >> 3, c = (idx & 7) * 8;
            *(bf16x8*)(As + r*72 + c) =
                *(const bf16x8*)(Ob + ((size_t)(bs0 + r)) * 512 + k0 + c);
            *(bf16x8*)(Bs + r*72 + c) =
                *(const bf16x8*)(WOT + (size_t)r * Dn + k0 + c);
        }
        __syncthreads();
        #pragma unroll
        for (int kc = 0; kc < 2; ++kc) {
            bf16x8 a = *(const bf16x8*)(As + (16*w + qh)*72 + 32*kc + 8*g);
            #pragma unroll
            for (int n = 0; n < 4; ++n) {
                bf16x8 bb = *(const bf16x8*)(Bs + (16*n + qh)*72 + 32*kc + 8*g);
                acc[n] = __builtin_amdgcn_mfma_f32_16x16x32_bf16(a, bb, acc[n], 0, 0, 0);
            }
        }
    }
    // C: col=lane&15 -> n-col = 16nt+qh ; row = 4g+reg -> m = 16w+4g+r
    for (int n = 0; n < 4; ++n)
        for (int r = 0; r < 4; ++r)
            out[((size_t)(bs0 + 16*w + 4*g + r)) * 64 + 16*n + qh] = acc[n][r];
}

extern "C" void kernel_launch(void* const* d_in, const int* in_sizes, int n_in,
                              void* d_out, int out_size, void* d_ws, size_t ws_size,
                              hipStream_t stream)
{
    const float* x  = (const float*)d_in[0];
    const float* WQ = (const float*)d_in[1];
    const float* WK = (const float*)d_in[2];
    const float* WV = (const float*)d_in[3];
    const float* WO = (const float*)d_in[4];
    float* out = (float*)d_out;

    const size_t NQ = (size_t)Bn * Hn * Sn * LATn;     // 8,388,608
    char* p = (char*)d_ws;
    unsigned short* Qb  = (unsigned short*)p;           p += NQ * 2;            // 16MB
    unsigned short* Kb  = (unsigned short*)p;           p += NQ * 2;            // 16MB
    unsigned short* VT  = (unsigned short*)p;           p += NQ * 2;            // 16MB
    unsigned short* WT  = (unsigned short*)p;           p += ((size_t)Hn*192*Dn + 64*Dn) * 2;
    unsigned short* Ob  = (unsigned short*)p;                                   // 16MB
    unsigned short* WOT = WT + (size_t)Hn * 192 * Dn;

    wprep     <<<dim3(8, 25),         256, 0, stream>>>(WQ, WK, WV, WO, WT);
    qkv_mfma  <<<dim3(Sn/64, Bn),     512, 0, stream>>>(x, WT, Qb, Kb, VT);
    flash_mfma<<<dim3(Sn/256, Bn*Hn), 512, 0, stream>>>(Qb, Kb, VT, Ob);
    out_mfma  <<<dim3(Bn*Sn/64),      256, 0, stream>>>(Ob, WOT, out);
}

// Round 3
// 222.995 us; speedup vs baseline: 1.0523x; 1.0523x over previous
//
#include <hip/hip_runtime.h>
#include <hip/hip_bf16.h>
#include <math.h>

// MHA B=8,S=2048,D=512,H=8,LAT=64,OUT=64. fp32 in/out.
// R16: qkv reverted to R14 (R15's 1-block/CU latency-bound h-loop regressed).
// flash rebuilt: 64 q-rows/wave (4 q-sets), 512 q/block, grid (4,64)=1 block/CU.
// K/V LDS fragment reads amortized 2x vs R14 (per-CU: 192 b128 vs 320 per tile)
// -> LDS port (the measured bottleneck, MfmaUtil 28%) now ~balanced with MFMA.
// Per-tile compute ~2500cy per barrier hides prefetch latency (no R15 trap).
static constexpr int Bn = 8, Sn = 2048, Dn = 512, Hn = 8, LATn = 64, OUTn = 64;

typedef short  bf16x8 __attribute__((ext_vector_type(8)));
typedef float  f32x4  __attribute__((ext_vector_type(4)));

__device__ __forceinline__ unsigned short f2bf(float f) {   // RNE (prep kernels)
    union { float f; unsigned int i; } v; v.f = f;
    unsigned int x = v.i;
    return (unsigned short)((x + 0x7FFFu + ((x >> 16) & 1u)) >> 16);
}
// pack two floats -> two bf16 (round-half-up: bias 2^-17 rel, ~RNE quality)
__device__ __forceinline__ unsigned int pack2bf(float a, float b) {
    unsigned int ua = __float_as_uint(a) + 0x8000u;
    unsigned int ub = __float_as_uint(b) + 0x8000u;
    return (ua >> 16) | (ub & 0xFFFF0000u);
}

#if __has_builtin(__builtin_amdgcn_exp2f)
#define EXP2(x) __builtin_amdgcn_exp2f(x)
#else
#define EXP2(x) exp2f(x)
#endif

// async 16B global->LDS; vmcnt-tracked; LDS dest = wave-uniform base + lane*16
__device__ __forceinline__ void gl_lds16(const void* g, void* l) {
    __builtin_amdgcn_global_load_lds(
        (const __attribute__((address_space(1))) unsigned int*)g,
        (__attribute__((address_space(3))) unsigned int*)l, 16, 0, 0);
}

// ---------------- Kernel 0: weight prep -------------------------------------
// WT[h][192][512] bf16 (Q slice scaled by 0.125*log2e), then WOT[64][512].
__global__ __launch_bounds__(256) void wprep(
    const float* __restrict__ WQ, const float* __restrict__ WK,
    const float* __restrict__ WV, const float* __restrict__ WO,
    unsigned short* __restrict__ WT)
{
    __shared__ float tile[64][65];
    const int t  = threadIdx.x;
    const int d0 = blockIdx.x * 64;
    const int yy = blockIdx.y;

    const float* W; float scale = 1.0f; size_t dstbase;
    if (yy < 24) {
        int h = yy / 3, which = yy % 3;
        W = (which == 0) ? WQ : (which == 1) ? WK : WV;
        W += (size_t)h * Dn * 64;
        if (which == 0) scale = 0.125f * 1.44269504088896f;   // fold 1/8 * log2(e)
        dstbase = ((size_t)h * 192 + which * 64) * Dn;
    } else {
        W = WO;                                                // [512][64]
        dstbase = (size_t)8 * 192 * Dn;                        // WOT after QKV
    }

    for (int i = 0; i < 4; ++i) {
        int idx = i * 256 + t;
        int r = idx >> 4, c = (idx & 15) * 4;
        float4 u = *(const float4*)(W + (size_t)(d0 + r) * 64 + c);
        tile[r][c] = u.x; tile[r][c+1] = u.y; tile[r][c+2] = u.z; tile[r][c+3] = u.w;
    }
    __syncthreads();
    const int n = t & 63, dd = t >> 6;
    unsigned short pk[16];
    for (int i = 0; i < 16; ++i) pk[i] = f2bf(tile[dd*16 + i][n] * scale);
    size_t dst = dstbase + (size_t)n * Dn + d0 + dd * 16;
    *(bf16x8*)(WT + dst)     = *(bf16x8*)(pk);
    *(bf16x8*)(WT + dst + 8) = *(bf16x8*)(pk + 8);
}

// ---------------- Kernel 1: MFMA QKV projection (R14, reverted) -------------
__global__ __launch_bounds__(256) void qkv_mfma(
    const float* __restrict__ x, const unsigned short* __restrict__ WT,
    unsigned short* __restrict__ Qb, unsigned short* __restrict__ Kb,
    unsigned short* __restrict__ VT)
{
    __shared__ __align__(16) unsigned short lds[64*72 + 192*72];
    unsigned short* Xs = lds;
    unsigned short* Ws = lds + 64*72;
    unsigned short* L  = lds;

    const int t  = threadIdx.x;
    const int w  = t >> 6, ln = t & 63;
    const int nl = ln & 15, g = ln >> 4;
    const int bh = blockIdx.y, b = bh >> 3, h = bh & 7;
    const int s0 = blockIdx.x * 64;

    f32x4 acc[4][3];
    for (int m = 0; m < 4; ++m)
        for (int j = 0; j < 3; ++j) acc[m][j] = (f32x4){0.f, 0.f, 0.f, 0.f};

    for (int k0 = 0; k0 < Dn; k0 += 64) {
        __syncthreads();
        for (int i = 0; i < 2; ++i) {              // x tile fp32 -> bf16 (pack2)
            int idx = i * 256 + t;
            int r = idx >> 3, c = (idx & 7) * 8;
            const float* src = x + ((size_t)(b * Sn + s0 + r)) * Dn + k0 + c;
            float4 u0 = *(const float4*)(src);
            float4 u1 = *(const float4*)(src + 4);
            unsigned int pk[4] = { pack2bf(u0.x, u0.y), pack2bf(u0.z, u0.w),
                                   pack2bf(u1.x, u1.y), pack2bf(u1.z, u1.w) };
            *(bf16x8*)(Xs + r*72 + c) = *(bf16x8*)pk;
        }
        for (int i = 0; i < 6; ++i) {              // WT tile 192x64
            int idx = i * 256 + t;
            int r = idx >> 3, c = (idx & 7) * 8;
            *(bf16x8*)(Ws + r*72 + c) =
                *(const bf16x8*)(WT + ((size_t)h * 192 + r) * Dn + k0 + c);
        }
        __syncthreads();
        #pragma unroll
        for (int kc = 0; kc < 2; ++kc) {
            bf16x8 a[4], bb[3];
            for (int m = 0; m < 4; ++m)
                a[m]  = *(const bf16x8*)(Xs + (16*m + nl)*72 + 32*kc + 8*g);
            for (int j = 0; j < 3; ++j)
                bb[j] = *(const bf16x8*)(Ws + ((3*w + j)*16 + nl)*72 + 32*kc + 8*g);
            for (int m = 0; m < 4; ++m)
                for (int j = 0; j < 3; ++j)
                    acc[m][j] = __builtin_amdgcn_mfma_f32_16x16x32_bf16(
                                    a[m], bb[j], acc[m][j], 0, 0, 0);
        }
    }
    __syncthreads();
    for (int m = 0; m < 4; ++m)                    // C: col=lane&15, row=4g+reg
        for (int j = 0; j < 3; ++j) {
            int n = 48*w + 16*j + nl;
            for (int r = 0; r < 4; ++r)
                L[(16*m + 4*g + r)*200 + n] = f2bf(acc[m][j][r]);
        }
    __syncthreads();
    for (int i = 0; i < 4; ++i) {                  // Qb/Kb row-major
        int idx = i * 256 + t;
        int r = idx >> 4, c = (idx & 15) * 8;
        bf16x8 v = *(const bf16x8*)(L + r*200 + c);
        size_t o = ((size_t)bh * Sn + s0 + r) * 64;
        if (c < 64) *(bf16x8*)(Qb + o + c)      = v;
        else        *(bf16x8*)(Kb + o + c - 64) = v;
    }
    {                                              // VT[bh][o][s]
        int o = t & 63, cc = t >> 6;
        unsigned short pk[16];
        for (int i = 0; i < 16; ++i) pk[i] = L[(16*cc + i)*200 + 128 + o];
        size_t dst = ((size_t)bh * 64 + o) * Sn + s0 + 16*cc;
        *(bf16x8*)(VT + dst)     = *(bf16x8*)(pk);
        *(bf16x8*)(VT + dst + 8) = *(bf16x8*)(pk + 8);
    }
}

// ---------------- Kernel 2: MFMA flash attention (R16: 64 q-rows/wave) ------
// 8 waves x 64 q-rows (4 q-sets); K/V async-staged (global_load_lds, dbuf,
// XOR swizzle); one barrier per k-tile; P via per-wave swizzled Pt (8 KB/wave);
// O stored direct. K/V fragment reads amortized over 4 q-sets.
__global__ __launch_bounds__(512, 2) void flash_mfma(
    const unsigned short* __restrict__ Qb,
    const unsigned short* __restrict__ Kb,
    const unsigned short* __restrict__ VT,
    unsigned short* __restrict__ Ob)
{
    __shared__ __align__(16) unsigned short KV[2][2][4096];   // 32 KB
    __shared__ __align__(16) unsigned short Pt[8][4096];      // 64 KB, per-wave

    const int t  = threadIdx.x;
    const int w  = t >> 6, ln = t & 63;
    const int qh = ln & 15, g = (ln >> 4) & 3;
    const int bh = blockIdx.y, b = bh >> 3, h = bh & 7;
    const int q0 = blockIdx.x * 512;
    const int qw = q0 + 64 * w;                    // this wave's 64 q rows

    // Q fragments: 4 q-sets x 2 kc (scaled by 0.125*log2e at prep time)
    bf16x8 bq[4][2];
    #pragma unroll
    for (int qs = 0; qs < 4; ++qs) {
        const unsigned short* qp =
            Qb + ((size_t)bh * Sn + qw + 16*qs + qh) * 64 + 8*g;
        bq[qs][0] = *(const bf16x8*)(qp);
        bq[qs][1] = *(const bf16x8*)(qp + 32);
    }

    // staging: thread t owns 16B chunk t of K and of V (512 chunks each).
    // source col pre-swizzled so linear LDS + swizzled read = coherent (G21).
    const int r0 = t >> 3;                         // tile row 0..63
    const int cs = (t & 7) ^ (r0 & 7);             // swizzled source chunk col
    const unsigned short* kg = Kb + ((size_t)bh * Sn + r0) * 64 + cs * 8;
    const unsigned short* vg = VT + ((size_t)bh * 64 + r0) * Sn + cs * 8;

    // fragment read offsets (shorts) inside a 64x64 tile: row=16f+qh,
    // chunk col (4kc+g)^(qh&7); +f*1024 folds into ds offset imm.
    const int swz8  = (qh & 7) * 8;                // shorts-XOR for 16B chunks
    const int koff0 = qh*64 + (((g    ) ^ (qh & 7)) * 8);
    const int koff1 = qh*64 + (((4 + g) ^ (qh & 7)) * 8);

    f32x4 o_acc[4][4];
    #pragma unroll
    for (int qs = 0; qs < 4; ++qs)
        #pragma unroll
        for (int f = 0; f < 4; ++f) o_acc[qs][f] = (f32x4){0.f, 0.f, 0.f, 0.f};
    float l_run[4] = {0.f, 0.f, 0.f, 0.f};

    // prologue: stage tile 0 into buf 0 (dest base wave-uniform, lane*16 auto)
    gl_lds16(kg, &KV[0][0][w * 512]);
    gl_lds16(vg, &KV[0][1][w * 512]);
    __syncthreads();

    int buf = 0;
    for (int kt = 0; kt < Sn / 64; ++kt) {
        if (kt < Sn / 64 - 1) {                    // prefetch next tile (async)
            kg += 4096; vg += 64;
            gl_lds16(kg, &KV[buf ^ 1][0][w * 512]);
            gl_lds16(vg, &KV[buf ^ 1][1][w * 512]);
        }
        const unsigned short* Kt = KV[buf][0];
        const unsigned short* Vt = KV[buf][1];

        // QK^T: st[qs][f] = S[k=16f+4g+r][q=16qs+qh]
        f32x4 st[4][4];
        #pragma unroll
        for (int qs = 0; qs < 4; ++qs)
            #pragma unroll
            for (int f = 0; f < 4; ++f) st[qs][f] = (f32x4){0.f, 0.f, 0.f, 0.f};
        #pragma unroll
        for (int kc = 0; kc < 2; ++kc) {
            const int ko = kc ? koff1 : koff0;
            bf16x8 a0 = *(const bf16x8*)(Kt + ko);
            bf16x8 a1 = *(const bf16x8*)(Kt + ko + 1024);
            bf16x8 a2 = *(const bf16x8*)(Kt + ko + 2048);
            bf16x8 a3 = *(const bf16x8*)(Kt + ko + 3072);
            #pragma unroll
            for (int qs = 0; qs < 4; ++qs) {
                st[qs][0] = __builtin_amdgcn_mfma_f32_16x16x32_bf16(a0, bq[qs][kc], st[qs][0], 0, 0, 0);
                st[qs][1] = __builtin_amdgcn_mfma_f32_16x16x32_bf16(a1, bq[qs][kc], st[qs][1], 0, 0, 0);
                st[qs][2] = __builtin_amdgcn_mfma_f32_16x16x32_bf16(a2, bq[qs][kc], st[qs][2], 0, 0, 0);
                st[qs][3] = __builtin_amdgcn_mfma_f32_16x16x32_bf16(a3, bq[qs][kc], st[qs][3], 0, 0, 0);
            }
        }

        // no-max softmax: P = exp2(s'); write bf16 P to swizzled Pt (per-wave,
        // DS in-order within wave -> no barrier needed before PV reads)
        #pragma unroll
        for (int qs = 0; qs < 4; ++qs) {
            float ls = 0.f;
            unsigned short* pw = Pt[w] + qs*1024 + qh*64;
            #pragma unroll
            for (int f = 0; f < 4; ++f) {
                float p0 = EXP2(st[qs][f][0]);
                float p1 = EXP2(st[qs][f][1]);
                float p2 = EXP2(st[qs][f][2]);
                float p3 = EXP2(st[qs][f][3]);
                ls += (p0 + p1) + (p2 + p3);
                *(uint2*)(pw + ((16*f + 4*g) ^ swz8)) =
                    make_uint2(pack2bf(p0, p1), pack2bf(p2, p3));
            }
            ls += __shfl_xor(ls, 16);
            ls += __shfl_xor(ls, 32);
            l_run[qs] += ls;
        }

        // PV: o_acc[qs][f] += V[o=16f+qh][k] * P[k][q]
        #pragma unroll
        for (int kc = 0; kc < 2; ++kc) {
            const int ko = kc ? koff1 : koff0;
            bf16x8 v0 = *(const bf16x8*)(Vt + ko);
            bf16x8 v1 = *(const bf16x8*)(Vt + ko + 1024);
            bf16x8 v2 = *(const bf16x8*)(Vt + ko + 2048);
            bf16x8 v3 = *(const bf16x8*)(Vt + ko + 3072);
            #pragma unroll
            for (int qs = 0; qs < 4; ++qs) {
                bf16x8 bp = *(const bf16x8*)(Pt[w] + qs*1024 + qh*64
                                             + ((32*kc + 8*g) ^ swz8));
                o_acc[qs][0] = __builtin_amdgcn_mfma_f32_16x16x32_bf16(v0, bp, o_acc[qs][0], 0, 0, 0);
                o_acc[qs][1] = __builtin_amdgcn_mfma_f32_16x16x32_bf16(v1, bp, o_acc[qs][1], 0, 0, 0);
                o_acc[qs][2] = __builtin_amdgcn_mfma_f32_16x16x32_bf16(v2, bp, o_acc[qs][2], 0, 0, 0);
                o_acc[qs][3] = __builtin_amdgcn_mfma_f32_16x16x32_bf16(v3, bp, o_acc[qs][3], 0, 0, 0);
            }
        }

        __syncthreads();   // drains vmcnt (next tile staged) + all reads of buf
        buf ^= 1;
    }

    // epilogue: O/l -> bf16 concat layout, direct from registers
    #pragma unroll
    for (int qs = 0; qs < 4; ++qs) {
        float inv_l = 1.f / l_run[qs];
        unsigned short* op = Ob
            + ((size_t)(b * Sn + q0 + 64*w + 16*qs + qh)) * 512 + h*64 + 4*g;
        #pragma unroll
        for (int f = 0; f < 4; ++f) {
            unsigned int lo = pack2bf(o_acc[qs][f][0] * inv_l, o_acc[qs][f][1] * inv_l);
            unsigned int hi = pack2bf(o_acc[qs][f][2] * inv_l, o_acc[qs][f][3] * inv_l);
            *(uint2*)(op + 16*f) = make_uint2(lo, hi);
        }
    }
}

// ---------------- Kernel 3: MFMA output projection --------------------------
// out[bs][n] = Ob[bs][0:512] @ WOT^T ; A=Ob rows, B=WOT[n][k]. fp32 out.
__global__ __launch_bounds__(256) void out_mfma(
    const unsigned short* __restrict__ Ob, const unsigned short* __restrict__ WOT,
    float* __restrict__ out)
{
    __shared__ __align__(16) unsigned short As[64 * 72];
    __shared__ __align__(16) unsigned short Bs[64 * 72];

    const int t  = threadIdx.x;
    const int w  = t >> 6, ln = t & 63;
    const int qh = ln & 15, g = ln >> 4;
    const int bs0 = blockIdx.x * 64;

    f32x4 acc[4];
    for (int n = 0; n < 4; ++n) acc[n] = (f32x4){0.f, 0.f, 0.f, 0.f};

    for (int k0 = 0; k0 < 512; k0 += 64) {
        __syncthreads();
        for (int i = 0; i < 2; ++i) {
            int idx = i * 256 + t;
            int r = idx >> 3, c = (idx & 7) * 8;
            *(bf16x8*)(As + r*72 + c) =
                *(const bf16x8*)(Ob + ((size_t)(bs0 + r)) * 512 + k0 + c);
            *(bf16x8*)(Bs + r*72 + c) =
                *(const bf16x8*)(WOT + (size_t)r * Dn + k0 + c);
        }
        __syncthreads();
        #pragma unroll
        for (int kc = 0; kc < 2; ++kc) {
            bf16x8 a = *(const bf16x8*)(As + (16*w + qh)*72 + 32*kc + 8*g);
            #pragma unroll
            for (int n = 0; n < 4; ++n) {
                bf16x8 bb = *(const bf16x8*)(Bs + (16*n + qh)*72 + 32*kc + 8*g);
                acc[n] = __builtin_amdgcn_mfma_f32_16x16x32_bf16(a, bb, acc[n], 0, 0, 0);
            }
        }
    }
    // C: col=lane&15 -> n-col = 16nt+qh ; row = 4g+reg -> m = 16w+4g+r
    for (int n = 0; n < 4; ++n)
        for (int r = 0; r < 4; ++r)
            out[((size_t)(bs0 + 16*w + 4*g + r)) * 64 + 16*n + qh] = acc[n][r];
}

extern "C" void kernel_launch(void* const* d_in, const int* in_sizes, int n_in,
                              void* d_out, int out_size, void* d_ws, size_t ws_size,
                              hipStream_t stream)
{
    const float* x  = (const float*)d_in[0];
    const float* WQ = (const float*)d_in[1];
    const float* WK = (const float*)d_in[2];
    const float* WV = (const float*)d_in[3];
    const float* WO = (const float*)d_in[4];
    float* out = (float*)d_out;

    const size_t NQ = (size_t)Bn * Hn * Sn * LATn;     // 8,388,608
    char* p = (char*)d_ws;
    unsigned short* Qb  = (unsigned short*)p;           p += NQ * 2;            // 16MB
    unsigned short* Kb  = (unsigned short*)p;           p += NQ * 2;            // 16MB
    unsigned short* VT  = (unsigned short*)p;           p += NQ * 2;            // 16MB
    unsigned short* WT  = (unsigned short*)p;           p += ((size_t)Hn*192*Dn + 64*Dn) * 2;
    unsigned short* Ob  = (unsigned short*)p;                                   // 16MB
    unsigned short* WOT = WT + (size_t)Hn * 192 * Dn;

    wprep     <<<dim3(8, 25),         256, 0, stream>>>(WQ, WK, WV, WO, WT);
    qkv_mfma  <<<dim3(Sn/64, Bn*Hn),  256, 0, stream>>>(x, WT, Qb, Kb, VT);
    flash_mfma<<<dim3(Sn/512, Bn*Hn), 512, 0, stream>>>(Qb, Kb, VT, Ob);
    out_mfma  <<<dim3(Bn*Sn/64),      256, 0, stream>>>(Ob, WOT, out);
}

// Round 4
// 207.109 us; speedup vs baseline: 1.1330x; 1.0767x over previous
//
#include <hip/hip_runtime.h>
#include <hip/hip_bf16.h>
#include <math.h>

// MHA B=8,S=2048,D=512,H=8,LAT=64,OUT=64. fp32 in/out.
// R17: P kept ENTIRELY in registers. VT stored k-permuted (sigma within each
// 32-col block) so the PV B-fragment slots coincide with the QK^T C-layout the
// lane already holds: bp[kc] = pack(st[2kc][0..3], st[2kc+1][0..3]), lane-local.
// Removes Pt LDS (64KB->0), its 2^22 conflict cycles, and 24 LDS ops/wave-tile.
// Flash: 4 waves x 64 q-rows, grid (8,64)=512 blocks = 2 independent blocks/CU.
// sigma applied in qkv's VT epilogue (already scalar reads -> zero cost).
static constexpr int Bn = 8, Sn = 2048, Dn = 512, Hn = 8, LATn = 64, OUTn = 64;

typedef short  bf16x8 __attribute__((ext_vector_type(8)));
typedef float  f32x4  __attribute__((ext_vector_type(4)));

__device__ __forceinline__ unsigned short f2bf(float f) {   // RNE (prep kernels)
    union { float f; unsigned int i; } v; v.f = f;
    unsigned int x = v.i;
    return (unsigned short)((x + 0x7FFFu + ((x >> 16) & 1u)) >> 16);
}
// pack two floats -> two bf16 (round-half-up: bias 2^-17 rel, ~RNE quality)
__device__ __forceinline__ unsigned int pack2bf(float a, float b) {
    unsigned int ua = __float_as_uint(a) + 0x8000u;
    unsigned int ub = __float_as_uint(b) + 0x8000u;
    return (ua >> 16) | (ub & 0xFFFF0000u);
}

#if __has_builtin(__builtin_amdgcn_exp2f)
#define EXP2(x) __builtin_amdgcn_exp2f(x)
#else
#define EXP2(x) exp2f(x)
#endif

// async 16B global->LDS; vmcnt-tracked; LDS dest = wave-uniform base + lane*16
__device__ __forceinline__ void gl_lds16(const void* g, void* l) {
    __builtin_amdgcn_global_load_lds(
        (const __attribute__((address_space(1))) unsigned int*)g,
        (__attribute__((address_space(3))) unsigned int*)l, 16, 0, 0);
}

// ---------------- Kernel 0: weight prep -------------------------------------
// WT[h][192][512] bf16 (Q slice scaled by 0.125*log2e), then WOT[64][512].
__global__ __launch_bounds__(256) void wprep(
    const float* __restrict__ WQ, const float* __restrict__ WK,
    const float* __restrict__ WV, const float* __restrict__ WO,
    unsigned short* __restrict__ WT)
{
    __shared__ float tile[64][65];
    const int t  = threadIdx.x;
    const int d0 = blockIdx.x * 64;
    const int yy = blockIdx.y;

    const float* W; float scale = 1.0f; size_t dstbase;
    if (yy < 24) {
        int h = yy / 3, which = yy % 3;
        W = (which == 0) ? WQ : (which == 1) ? WK : WV;
        W += (size_t)h * Dn * 64;
        if (which == 0) scale = 0.125f * 1.44269504088896f;   // fold 1/8 * log2(e)
        dstbase = ((size_t)h * 192 + which * 64) * Dn;
    } else {
        W = WO;                                                // [512][64]
        dstbase = (size_t)8 * 192 * Dn;                        // WOT after QKV
    }

    for (int i = 0; i < 4; ++i) {
        int idx = i * 256 + t;
        int r = idx >> 4, c = (idx & 15) * 4;
        float4 u = *(const float4*)(W + (size_t)(d0 + r) * 64 + c);
        tile[r][c] = u.x; tile[r][c+1] = u.y; tile[r][c+2] = u.z; tile[r][c+3] = u.w;
    }
    __syncthreads();
    const int n = t & 63, dd = t >> 6;
    unsigned short pk[16];
    for (int i = 0; i < 16; ++i) pk[i] = f2bf(tile[dd*16 + i][n] * scale);
    size_t dst = dstbase + (size_t)n * Dn + d0 + dd * 16;
    *(bf16x8*)(WT + dst)     = *(bf16x8*)(pk);
    *(bf16x8*)(WT + dst + 8) = *(bf16x8*)(pk + 8);
}

// ---------------- Kernel 1: MFMA QKV projection (R14 + sigma on VT) ---------
__global__ __launch_bounds__(256) void qkv_mfma(
    const float* __restrict__ x, const unsigned short* __restrict__ WT,
    unsigned short* __restrict__ Qb, unsigned short* __restrict__ Kb,
    unsigned short* __restrict__ VT)
{
    __shared__ __align__(16) unsigned short lds[64*72 + 192*72];
    unsigned short* Xs = lds;
    unsigned short* Ws = lds + 64*72;
    unsigned short* L  = lds;

    const int t  = threadIdx.x;
    const int w  = t >> 6, ln = t & 63;
    const int nl = ln & 15, g = ln >> 4;
    const int bh = blockIdx.y, b = bh >> 3, h = bh & 7;
    const int s0 = blockIdx.x * 64;

    f32x4 acc[4][3];
    for (int m = 0; m < 4; ++m)
        for (int j = 0; j < 3; ++j) acc[m][j] = (f32x4){0.f, 0.f, 0.f, 0.f};

    for (int k0 = 0; k0 < Dn; k0 += 64) {
        __syncthreads();
        for (int i = 0; i < 2; ++i) {              // x tile fp32 -> bf16 (pack2)
            int idx = i * 256 + t;
            int r = idx >> 3, c = (idx & 7) * 8;
            const float* src = x + ((size_t)(b * Sn + s0 + r)) * Dn + k0 + c;
            float4 u0 = *(const float4*)(src);
            float4 u1 = *(const float4*)(src + 4);
            unsigned int pk[4] = { pack2bf(u0.x, u0.y), pack2bf(u0.z, u0.w),
                                   pack2bf(u1.x, u1.y), pack2bf(u1.z, u1.w) };
            *(bf16x8*)(Xs + r*72 + c) = *(bf16x8*)pk;
        }
        for (int i = 0; i < 6; ++i) {              // WT tile 192x64
            int idx = i * 256 + t;
            int r = idx >> 3, c = (idx & 7) * 8;
            *(bf16x8*)(Ws + r*72 + c) =
                *(const bf16x8*)(WT + ((size_t)h * 192 + r) * Dn + k0 + c);
        }
        __syncthreads();
        #pragma unroll
        for (int kc = 0; kc < 2; ++kc) {
            bf16x8 a[4], bb[3];
            for (int m = 0; m < 4; ++m)
                a[m]  = *(const bf16x8*)(Xs + (16*m + nl)*72 + 32*kc + 8*g);
            for (int j = 0; j < 3; ++j)
                bb[j] = *(const bf16x8*)(Ws + ((3*w + j)*16 + nl)*72 + 32*kc + 8*g);
            for (int m = 0; m < 4; ++m)
                for (int j = 0; j < 3; ++j)
                    acc[m][j] = __builtin_amdgcn_mfma_f32_16x16x32_bf16(
                                    a[m], bb[j], acc[m][j], 0, 0, 0);
        }
    }
    __syncthreads();
    for (int m = 0; m < 4; ++m)                    // C: col=lane&15, row=4g+reg
        for (int j = 0; j < 3; ++j) {
            int n = 48*w + 16*j + nl;
            for (int r = 0; r < 4; ++r)
                L[(16*m + 4*g + r)*200 + n] = f2bf(acc[m][j][r]);
        }
    __syncthreads();
    for (int i = 0; i < 4; ++i) {                  // Qb/Kb row-major
        int idx = i * 256 + t;
        int r = idx >> 4, c = (idx & 15) * 8;
        bf16x8 v = *(const bf16x8*)(L + r*200 + c);
        size_t o = ((size_t)bh * Sn + s0 + r) * 64;
        if (c < 64) *(bf16x8*)(Qb + o + c)      = v;
        else        *(bf16x8*)(Kb + o + c - 64) = v;
    }
    {   // VT[bh][o][s], sigma k-permuted within 32-blocks (for in-reg P in flash)
        // stored pos p=16cc+i holds s_local = 32(cc>>1)+16((i>>2)&1)+8(cc&1)
        //                                     +4((i>>3)&1)+(i&3)
        int o = t & 63, cc = t >> 6;
        unsigned short pk[16];
        for (int i = 0; i < 16; ++i) {
            int srow = 32*(cc>>1) + 16*((i>>2)&1) + 8*(cc&1) + 4*((i>>3)&1) + (i&3);
            pk[i] = L[srow*200 + 128 + o];
        }
        size_t dst = ((size_t)bh * 64 + o) * Sn + s0 + 16*cc;
        *(bf16x8*)(VT + dst)     = *(bf16x8*)(pk);
        *(bf16x8*)(VT + dst + 8) = *(bf16x8*)(pk + 8);
    }
}

// ---------------- Kernel 2: MFMA flash attention (R17: in-register P) -------
// 4 waves x 64 q-rows (4 q-sets), 256 q/block, grid (8,64) = 2 blocks/CU.
// K/V async-staged (global_load_lds, dbuf, XOR swizzle); one barrier per tile.
// P never touches LDS: bp[kc] = pack(st[2kc][0..3], st[2kc+1][0..3]) matched to
// sigma-permuted V columns. l-reduction shuffles hoisted out of the k-loop.
__global__ __launch_bounds__(256, 2) void flash_mfma(
    const unsigned short* __restrict__ Qb,
    const unsigned short* __restrict__ Kb,
    const unsigned short* __restrict__ VT,
    unsigned short* __restrict__ Ob)
{
    __shared__ __align__(16) unsigned short KV[2][2][4096];   // 32 KB total

    const int t  = threadIdx.x;                    // 256 threads, 4 waves
    const int w  = t >> 6, ln = t & 63;
    const int qh = ln & 15, g = (ln >> 4) & 3;
    const int bh = blockIdx.y, b = bh >> 3, h = bh & 7;
    const int q0 = blockIdx.x * 256;
    const int qw = q0 + 64 * w;                    // this wave's 64 q rows

    // Q fragments: 4 q-sets x 2 kc (scaled by 0.125*log2e at prep time)
    bf16x8 bq[4][2];
    #pragma unroll
    for (int qs = 0; qs < 4; ++qs) {
        const unsigned short* qp =
            Qb + ((size_t)bh * Sn + qw + 16*qs + qh) * 64 + 8*g;
        bq[qs][0] = *(const bf16x8*)(qp);
        bq[qs][1] = *(const bf16x8*)(qp + 32);
    }

    // staging: 256 threads x 2 chunk-sets cover 512 chunks (8KB) per tile.
    // source col pre-swizzled: lds chunk (r,c) holds global chunk (r, c^(r&7)).
    const int r0a = t >> 3;                        // rows 0..31
    const int csa = (t & 7) ^ (r0a & 7);
    const int r0b = 32 + (t >> 3);                 // rows 32..63
    const int csb = (t & 7) ^ (r0b & 7);
    const unsigned short* kga = Kb + ((size_t)bh * Sn + r0a) * 64 + csa * 8;
    const unsigned short* kgb = Kb + ((size_t)bh * Sn + r0b) * 64 + csb * 8;
    const unsigned short* vga = VT + ((size_t)bh * 64 + r0a) * Sn + csa * 8;
    const unsigned short* vgb = VT + ((size_t)bh * 64 + r0b) * Sn + csb * 8;

    // fragment read offsets (shorts): row=16f+qh, chunk (4kc+g)^(qh&7)
    const int koff0 = qh*64 + (((g    ) ^ (qh & 7)) * 8);
    const int koff1 = qh*64 + (((4 + g) ^ (qh & 7)) * 8);

    f32x4 o_acc[4][4];
    #pragma unroll
    for (int qs = 0; qs < 4; ++qs)
        #pragma unroll
        for (int f = 0; f < 4; ++f) o_acc[qs][f] = (f32x4){0.f, 0.f, 0.f, 0.f};
    float l_run[4] = {0.f, 0.f, 0.f, 0.f};

    gl_lds16(kga, &KV[0][0][w * 512]);
    gl_lds16(kgb, &KV[0][0][2048 + w * 512]);
    gl_lds16(vga, &KV[0][1][w * 512]);
    gl_lds16(vgb, &KV[0][1][2048 + w * 512]);
    __syncthreads();

    int buf = 0;
    for (int kt = 0; kt < Sn / 64; ++kt) {
        if (kt < Sn / 64 - 1) {                    // prefetch next tile (async)
            kga += 4096; kgb += 4096; vga += 64; vgb += 64;
            gl_lds16(kga, &KV[buf ^ 1][0][w * 512]);
            gl_lds16(kgb, &KV[buf ^ 1][0][2048 + w * 512]);
            gl_lds16(vga, &KV[buf ^ 1][1][w * 512]);
            gl_lds16(vgb, &KV[buf ^ 1][1][2048 + w * 512]);
        }
        const unsigned short* Kt = KV[buf][0];
        const unsigned short* Vt = KV[buf][1];

        // QK^T: st[qs][f] = S[k=16f+4g+r][q=16qs+qh]
        f32x4 st[4][4];
        #pragma unroll
        for (int qs = 0; qs < 4; ++qs)
            #pragma unroll
            for (int f = 0; f < 4; ++f) st[qs][f] = (f32x4){0.f, 0.f, 0.f, 0.f};
        #pragma unroll
        for (int kc = 0; kc < 2; ++kc) {
            const int ko = kc ? koff1 : koff0;
            bf16x8 a0 = *(const bf16x8*)(Kt + ko);
            bf16x8 a1 = *(const bf16x8*)(Kt + ko + 1024);
            bf16x8 a2 = *(const bf16x8*)(Kt + ko + 2048);
            bf16x8 a3 = *(const bf16x8*)(Kt + ko + 3072);
            #pragma unroll
            for (int qs = 0; qs < 4; ++qs) {
                st[qs][0] = __builtin_amdgcn_mfma_f32_16x16x32_bf16(a0, bq[qs][kc], st[qs][0], 0, 0, 0);
                st[qs][1] = __builtin_amdgcn_mfma_f32_16x16x32_bf16(a1, bq[qs][kc], st[qs][1], 0, 0, 0);
                st[qs][2] = __builtin_amdgcn_mfma_f32_16x16x32_bf16(a2, bq[qs][kc], st[qs][2], 0, 0, 0);
                st[qs][3] = __builtin_amdgcn_mfma_f32_16x16x32_bf16(a3, bq[qs][kc], st[qs][3], 0, 0, 0);
            }
        }

        // no-max softmax fully in-register: P = exp2(s'); bp slot j of (kc,g)
        // holds P[k=32kc+16(j>>2)+4g+(j&3)] == sigma-permuted V column order.
        bf16x8 bp[4][2];
        #pragma unroll
        for (int qs = 0; qs < 4; ++qs) {
            float e0[4], e1[4], e2[4], e3[4];
            #pragma unroll
            for (int r = 0; r < 4; ++r) {
                e0[r] = EXP2(st[qs][0][r]);
                e1[r] = EXP2(st[qs][1][r]);
                e2[r] = EXP2(st[qs][2][r]);
                e3[r] = EXP2(st[qs][3][r]);
            }
            l_run[qs] += ((e0[0]+e0[1])+(e0[2]+e0[3])) + ((e1[0]+e1[1])+(e1[2]+e1[3]))
                       + ((e2[0]+e2[1])+(e2[2]+e2[3])) + ((e3[0]+e3[1])+(e3[2]+e3[3]));
            unsigned int p0[4] = { pack2bf(e0[0],e0[1]), pack2bf(e0[2],e0[3]),
                                   pack2bf(e1[0],e1[1]), pack2bf(e1[2],e1[3]) };
            unsigned int p1[4] = { pack2bf(e2[0],e2[1]), pack2bf(e2[2],e2[3]),
                                   pack2bf(e3[0],e3[1]), pack2bf(e3[2],e3[3]) };
            bp[qs][0] = *(bf16x8*)p0;
            bp[qs][1] = *(bf16x8*)p1;
        }

        // PV: o_acc[qs][f] += V[o=16f+qh][.] * P[.][q]  (slot-aligned via sigma)
        #pragma unroll
        for (int kc = 0; kc < 2; ++kc) {
            const int ko = kc ? koff1 : koff0;
            bf16x8 v0 = *(const bf16x8*)(Vt + ko);
            bf16x8 v1 = *(const bf16x8*)(Vt + ko + 1024);
            bf16x8 v2 = *(const bf16x8*)(Vt + ko + 2048);
            bf16x8 v3 = *(const bf16x8*)(Vt + ko + 3072);
            #pragma unroll
            for (int qs = 0; qs < 4; ++qs) {
                o_acc[qs][0] = __builtin_amdgcn_mfma_f32_16x16x32_bf16(v0, bp[qs][kc], o_acc[qs][0], 0, 0, 0);
                o_acc[qs][1] = __builtin_amdgcn_mfma_f32_16x16x32_bf16(v1, bp[qs][kc], o_acc[qs][1], 0, 0, 0);
                o_acc[qs][2] = __builtin_amdgcn_mfma_f32_16x16x32_bf16(v2, bp[qs][kc], o_acc[qs][2], 0, 0, 0);
                o_acc[qs][3] = __builtin_amdgcn_mfma_f32_16x16x32_bf16(v3, bp[qs][kc], o_acc[qs][3], 0, 0, 0);
            }
        }

        __syncthreads();   // drains vmcnt (next tile staged) + all reads of buf
        buf ^= 1;
    }

    // l cross-lane reduction (hoisted out of k-loop: linear in k -> legal)
    #pragma unroll
    for (int qs = 0; qs < 4; ++qs) {
        l_run[qs] += __shfl_xor(l_run[qs], 16);
        l_run[qs] += __shfl_xor(l_run[qs], 32);
    }

    // epilogue: O/l -> bf16 concat layout, direct from registers
    #pragma unroll
    for (int qs = 0; qs < 4; ++qs) {
        float inv_l = 1.f / l_run[qs];
        unsigned short* op = Ob
            + ((size_t)(b * Sn + q0 + 64*w + 16*qs + qh)) * 512 + h*64 + 4*g;
        #pragma unroll
        for (int f = 0; f < 4; ++f) {
            unsigned int lo = pack2bf(o_acc[qs][f][0] * inv_l, o_acc[qs][f][1] * inv_l);
            unsigned int hi = pack2bf(o_acc[qs][f][2] * inv_l, o_acc[qs][f][3] * inv_l);
            *(uint2*)(op + 16*f) = make_uint2(lo, hi);
        }
    }
}

// ---------------- Kernel 3: MFMA output projection --------------------------
// out[bs][n] = Ob[bs][0:512] @ WOT^T ; A=Ob rows, B=WOT[n][k]. fp32 out.
__global__ __launch_bounds__(256) void out_mfma(
    const unsigned short* __restrict__ Ob, const unsigned short* __restrict__ WOT,
    float* __restrict__ out)
{
    __shared__ __align__(16) unsigned short As[64 * 72];
    __shared__ __align__(16) unsigned short Bs[64 * 72];

    const int t  = threadIdx.x;
    const int w  = t >> 6, ln = t & 63;
    const int qh = ln & 15, g = ln >> 4;
    const int bs0 = blockIdx.x * 64;

    f32x4 acc[4];
    for (int n = 0; n < 4; ++n) acc[n] = (f32x4){0.f, 0.f, 0.f, 0.f};

    for (int k0 = 0; k0 < 512; k0 += 64) {
        __syncthreads();
        for (int i = 0; i < 2; ++i) {
            int idx = i * 256 + t;
            int r = idx >> 3, c = (idx & 7) * 8;
            *(bf16x8*)(As + r*72 + c) =
                *(const bf16x8*)(Ob + ((size_t)(bs0 + r)) * 512 + k0 + c);
            *(bf16x8*)(Bs + r*72 + c) =
                *(const bf16x8*)(WOT + (size_t)r * Dn + k0 + c);
        }
        __syncthreads();
        #pragma unroll
        for (int kc = 0; kc < 2; ++kc) {
            bf16x8 a = *(const bf16x8*)(As + (16*w + qh)*72 + 32*kc + 8*g);
            #pragma unroll
            for (int n = 0; n < 4; ++n) {
                bf16x8 bb = *(const bf16x8*)(Bs + (16*n + qh)*72 + 32*kc + 8*g);
                acc[n] = __builtin_amdgcn_mfma_f32_16x16x32_bf16(a, bb, acc[n], 0, 0, 0);
            }
        }
    }
    // C: col=lane&15 -> n-col = 16nt+qh ; row = 4g+reg -> m = 16w+4g+r
    for (int n = 0; n < 4; ++n)
        for (int r = 0; r < 4; ++r)
            out[((size_t)(bs0 + 16*w + 4*g + r)) * 64 + 16*n + qh] = acc[n][r];
}

extern "C" void kernel_launch(void* const* d_in, const int* in_sizes, int n_in,
                              void* d_out, int out_size, void* d_ws, size_t ws_size,
                              hipStream_t stream)
{
    const float* x  = (const float*)d_in[0];
    const float* WQ = (const float*)d_in[1];
    const float* WK = (const float*)d_in[2];
    const float* WV = (const float*)d_in[3];
    const float* WO = (const float*)d_in[4];
    float* out = (float*)d_out;

    const size_t NQ = (size_t)Bn * Hn * Sn * LATn;     // 8,388,608
    char* p = (char*)d_ws;
    unsigned short* Qb  = (unsigned short*)p;           p += NQ * 2;            // 16MB
    unsigned short* Kb  = (unsigned short*)p;           p += NQ * 2;            // 16MB
    unsigned short* VT  = (unsigned short*)p;           p += NQ * 2;            // 16MB
    unsigned short* WT  = (unsigned short*)p;           p += ((size_t)Hn*192*Dn + 64*Dn) * 2;
    unsigned short* Ob  = (unsigned short*)p;                                   // 16MB
    unsigned short* WOT = WT + (size_t)Hn * 192 * Dn;

    wprep     <<<dim3(8, 25),         256, 0, stream>>>(WQ, WK, WV, WO, WT);
    qkv_mfma  <<<dim3(Sn/64, Bn*Hn),  256, 0, stream>>>(x, WT, Qb, Kb, VT);
    flash_mfma<<<dim3(Sn/256, Bn*Hn), 256, 0, stream>>>(Qb, Kb, VT, Ob);
    out_mfma  <<<dim3(Bn*Sn/64),      256, 0, stream>>>(Ob, WOT, out);
}